// Round 8
// baseline (77.109 us; speedup 1.0000x reference)
//
#include <hip/hip_runtime.h>

// ImprovedBilateralFilter3D — 96^3 fp32, fused single kernel, v5 (resubmit;
// round 7 hit a broker timeout and this version never got measured).
//
// Per block: 32x8x4 output tile (1024 voxels), 256 threads.
//   Stage A: 36x12x8 volume tile (halo 2) -> LDS sv, zero outside bounds.
//   Stage B: separable Sobel plane-sweep over the 34x10 grad patch
//            (2 chunks of <=256 columns), rolling z-registers, writes
//            float4{gh,gw,gd,val} -> sq.
//   Stage C: bilateral; each thread owns a z-column of 4 voxels:
//            6 z-planes x 9 xy-neighbors = 54 ds_read_b128 for 4 outputs
//            (13.5 reads/voxel vs 22.5 in v4). Spatial term and log2(e)
//            folded into compile-time constants; one exp2 per neighbor.
// LDS: 13824 (sv) + 32640 (sq) = 46.5 KB -> 3 blocks/CU.
// NOTE: no min-waves hint in __launch_bounds__ — r5 showed (256,4) caps
// VGPR at 64 and spills ~270 MB to scratch (81 us kernel).

#define NV 96
#define NV2 (NV * NV)

#define TX 32
#define TY 8
#define TZ 4
#define VX (TX + 4)  // 36
#define VY (TY + 4)  // 12
#define VZ (TZ + 4)  // 8
#define GX (TX + 2)  // 34
#define GY (TY + 2)  // 10
#define GZ (TZ + 2)  // 6
#define NVOL (VX * VY * VZ)  // 3456
#define NCOL (GX * GY)       // 340

#define LOG2E 1.44269504088896340736f

__global__ __launch_bounds__(256) void fused_bilateral_kernel(
    const float* __restrict__ vol, float* __restrict__ out) {
    __shared__ float sv[VZ][VY][VX];   // raw volume, zero-padded
    __shared__ float4 sq[GZ][GY][GX];  // {gh, gw, gd, val}

    const int X0 = blockIdx.x * TX;
    const int Y0 = blockIdx.y * TY;
    const int Z0 = blockIdx.z * TZ;
    const int t = threadIdx.x;

    // ---- Stage A: volume tile + halo 2, zero outside global bounds ----
    for (int li = t; li < NVOL; li += 256) {
        int lx = li % VX;
        int lyz = li / VX;
        int ly = lyz % VY;
        int lz = lyz / VY;
        int gx = X0 - 2 + lx;
        int gy = Y0 - 2 + ly;
        int gz = Z0 - 2 + lz;
        float v = 0.0f;
        if (gx >= 0 && gx < NV && gy >= 0 && gy < NV && gz >= 0 && gz < NV)
            v = vol[gz * NV2 + gy * NV + gx];
        sv[lz][ly][lx] = v;
    }
    __syncthreads();

    // ---- Stage B: separable Sobel, z plane-sweep (2 column chunks) ----
#pragma unroll
    for (int base = 0; base < NCOL; base += 256) {
        int li = base + t;
        if (li < NCOL) {
            const int gx_ = li % GX;
            const int gy_ = li / GX;
            float s0 = 0.f, s1 = 0.f, s2 = 0.f;  // sm_y (x) sm_x per plane
            float w0 = 0.f, w1 = 0.f, w2 = 0.f;  // dy (x) sm_x
            float u0 = 0.f, u1 = 0.f, u2 = 0.f;  // sm_y (x) dx
            float v11p = 0.f;                    // prev-plane center value
#pragma unroll
            for (int p = 0; p < VZ; ++p) {
                float a00 = sv[p][gy_ + 0][gx_ + 0];
                float a01 = sv[p][gy_ + 0][gx_ + 1];
                float a02 = sv[p][gy_ + 0][gx_ + 2];
                float a10 = sv[p][gy_ + 1][gx_ + 0];
                float a11 = sv[p][gy_ + 1][gx_ + 1];
                float a12 = sv[p][gy_ + 1][gx_ + 2];
                float a20 = sv[p][gy_ + 2][gx_ + 0];
                float a21 = sv[p][gy_ + 2][gx_ + 1];
                float a22 = sv[p][gy_ + 2][gx_ + 2];
                float r0 = 0.25f * a00 + 0.5f * a01 + 0.25f * a02;
                float r1 = 0.25f * a10 + 0.5f * a11 + 0.25f * a12;
                float r2 = 0.25f * a20 + 0.5f * a21 + 0.25f * a22;
                float sxy = 0.25f * r0 + 0.5f * r1 + 0.25f * r2;  // sm sm
                float dyx = r0 - r2;                              // dy sm
                float dx0 = a00 - a02;
                float dx1 = a10 - a12;
                float dx2 = a20 - a22;
                float dxs = 0.25f * dx0 + 0.5f * dx1 + 0.25f * dx2;  // sm dx
                s0 = s1; s1 = s2; s2 = sxy;
                w0 = w1; w1 = w2; w2 = dyx;
                u0 = u1; u1 = u2; u2 = dxs;
                if (p >= 2) {
                    float gh = s0 - s2;                              // dz
                    float gw = 0.25f * w0 + 0.5f * w1 + 0.25f * w2;  // sm_z dy
                    float gd = 0.25f * u0 + 0.5f * u1 + 0.25f * u2;  // sm_z dx
                    sq[p - 2][gy_][gx_] = make_float4(gh, gw, gd, v11p);
                }
                v11p = a11;
            }
        }
    }
    __syncthreads();

    // ---- Stage C: bilateral, z-column of 4 voxels per thread ----
    const int tx = t & 31;
    const int ty = t >> 5;  // 0..7
    const int ox = X0 + tx;
    const int oy = Y0 + ty;

    // range coeff with log2(e) folded: w = 2^(SDC - g*RC)
    const float RC = LOG2E / (2.0f * 1.2f * 1.2f);

    // center packed grads: grad-local = tile-local + 1
    const float4 c0 = sq[1][ty + 1][tx + 1];
    const float4 c1 = sq[2][ty + 1][tx + 1];
    const float4 c2 = sq[3][ty + 1][tx + 1];
    const float4 c3 = sq[4][ty + 1][tx + 1];

    int nx[3], ny[3], nz[6];
#pragma unroll
    for (int d = 0; d < 3; ++d) {
        nx[d] = min(max(ox + d - 1, 0), NV - 1) - (X0 - 1);
        ny[d] = min(max(oy + d - 1, 0), NV - 1) - (Y0 - 1);
    }
#pragma unroll
    for (int p = 0; p < 6; ++p)
        nz[p] = min(max(Z0 + p - 1, 0), NV - 1) - (Z0 - 1);

    float num[4] = {0.f, 0.f, 0.f, 0.f};
    float den[4] = {0.f, 0.f, 0.f, 0.f};

#pragma unroll
    for (int p = 0; p < 6; ++p) {  // absolute plane Z0-1+p
#pragma unroll
        for (int iy = 0; iy < 3; ++iy) {
#pragma unroll
            for (int ix = 0; ix < 3; ++ix) {
                float4 q = sq[nz[p]][ny[iy]][nx[ix]];
#pragma unroll
                for (int k = 0; k < 4; ++k) {
                    const int dz = p - 1 - k;
                    if (dz >= -1 && dz <= 1) {
                        // spatial term, compile-time, log2e pre-folded
                        const float SDC =
                            -(float)(dz * dz + (iy - 1) * (iy - 1) +
                                     (ix - 1) * (ix - 1)) *
                            (LOG2E / (2.0f * 120.0f * 120.0f));
                        float4 c = (k == 0) ? c0 : (k == 1) ? c1
                                 : (k == 2) ? c2 : c3;
                        float a = c.x - q.x, b = c.y - q.y, e = c.z - q.z;
                        float g = a * a + b * b + e * e;
                        float w = __builtin_amdgcn_exp2f(fmaf(-g, RC, SDC));
                        num[k] += w * q.w;
                        den[k] += w;
                    }
                }
            }
        }
    }

#pragma unroll
    for (int k = 0; k < 4; ++k)
        out[(Z0 + k) * NV2 + oy * NV + ox] = num[k] / fmaxf(den[k], 1e-8f);
}

extern "C" void kernel_launch(void* const* d_in, const int* in_sizes, int n_in,
                              void* d_out, int out_size, void* d_ws, size_t ws_size,
                              hipStream_t stream) {
    const float* vol = (const float*)d_in[0];
    float* out = (float*)d_out;

    dim3 grid(NV / TX, NV / TY, NV / TZ);  // 3 x 12 x 24 = 864 blocks
    fused_bilateral_kernel<<<grid, dim3(256), 0, stream>>>(vol, out);
}

// Round 9
// 72.702 us; speedup vs baseline: 1.0606x; 1.0606x over previous
//
#include <hip/hip_runtime.h>

// ImprovedBilateralFilter3D — 96^3 fp32, fused single kernel, v6.
// = v4 (best measured: 71.2 us total) + two occupancy-neutral cuts:
//   * stage C pairs ADJACENT z (2*tzh, 2*tzh+1): 4 shared planes -> 36
//     ds_read_b128 per thread (was 45 with the (z, z+2) pairing).
//   * exp2 with log2(e) pre-folded into the spatial/range constants.
// Lessons kept: no min-waves launch_bounds (r5: VGPR cap -> 270 MB scratch
// spill); no instruction cuts that cost occupancy (r8: v5's 12-wave/CU
// variant lost 5 us despite 40% fewer LDS reads — kernel is latency-bound).
//
// Per block: 32x4x4 output tile (512 voxels), 256 threads.
//   Stage A: 36x8x8 volume tile (halo 2) -> LDS sv, zero outside bounds.
//   Stage B: separable Sobel plane-sweep, one thread per (x,y) of the 34x6
//            grad patch, rolling z-registers -> float4{gh,gw,gd,val} sq.
//   Stage C: bilateral; 2 adjacent voxels/thread.
// LDS: 9216 (sv) + 19584 (sq) = 28.8 KB -> 5 blocks/CU, 20 waves/CU.

#define NV 96
#define NV2 (NV * NV)

#define TX 32
#define TY 4
#define TZ 4
#define VX (TX + 4)  // 36
#define VY (TY + 4)  // 8
#define VZ (TZ + 4)  // 8
#define GX (TX + 2)  // 34
#define GY (TY + 2)  // 6
#define GZ (TZ + 2)  // 6
#define NVOL (VX * VY * VZ)  // 2304

#define LOG2E 1.44269504088896340736f

__global__ __launch_bounds__(256) void fused_bilateral_kernel(
    const float* __restrict__ vol, float* __restrict__ out) {
    __shared__ float sv[VZ][VY][VX];   // raw volume, zero-padded
    __shared__ float4 sq[GZ][GY][GX];  // {gh, gw, gd, val}

    const int X0 = blockIdx.x * TX;
    const int Y0 = blockIdx.y * TY;
    const int Z0 = blockIdx.z * TZ;
    const int t = threadIdx.x;

    // ---- Stage A: volume tile + halo 2, zero outside global bounds ----
    for (int li = t; li < NVOL; li += 256) {
        int lx = li % VX;
        int lyz = li / VX;
        int ly = lyz % VY;
        int lz = lyz / VY;
        int gx = X0 - 2 + lx;
        int gy = Y0 - 2 + ly;
        int gz = Z0 - 2 + lz;
        float v = 0.0f;
        if (gx >= 0 && gx < NV && gy >= 0 && gy < NV && gz >= 0 && gz < NV)
            v = vol[gz * NV2 + gy * NV + gx];
        sv[lz][ly][lx] = v;
    }
    __syncthreads();

    // ---- Stage B: separable Sobel, z plane-sweep ----
    if (t < GX * GY) {
        const int gx_ = t % GX;
        const int gy_ = t / GX;
        float s0 = 0.f, s1 = 0.f, s2 = 0.f;  // sm_y (x) sm_x per plane
        float w0 = 0.f, w1 = 0.f, w2 = 0.f;  // dy (x) sm_x
        float u0 = 0.f, u1 = 0.f, u2 = 0.f;  // sm_y (x) dx
        float v11p = 0.f;                    // prev-plane center value
#pragma unroll
        for (int p = 0; p < VZ; ++p) {
            float a00 = sv[p][gy_ + 0][gx_ + 0];
            float a01 = sv[p][gy_ + 0][gx_ + 1];
            float a02 = sv[p][gy_ + 0][gx_ + 2];
            float a10 = sv[p][gy_ + 1][gx_ + 0];
            float a11 = sv[p][gy_ + 1][gx_ + 1];
            float a12 = sv[p][gy_ + 1][gx_ + 2];
            float a20 = sv[p][gy_ + 2][gx_ + 0];
            float a21 = sv[p][gy_ + 2][gx_ + 1];
            float a22 = sv[p][gy_ + 2][gx_ + 2];
            float r0 = 0.25f * a00 + 0.5f * a01 + 0.25f * a02;
            float r1 = 0.25f * a10 + 0.5f * a11 + 0.25f * a12;
            float r2 = 0.25f * a20 + 0.5f * a21 + 0.25f * a22;
            float sxy = 0.25f * r0 + 0.5f * r1 + 0.25f * r2;  // sm sm
            float dyx = r0 - r2;                              // dy sm
            float dx0 = a00 - a02;
            float dx1 = a10 - a12;
            float dx2 = a20 - a22;
            float dxs = 0.25f * dx0 + 0.5f * dx1 + 0.25f * dx2;  // sm dx
            s0 = s1; s1 = s2; s2 = sxy;
            w0 = w1; w1 = w2; w2 = dyx;
            u0 = u1; u1 = u2; u2 = dxs;
            if (p >= 2) {
                float gh = s0 - s2;                              // dz
                float gw = 0.25f * w0 + 0.5f * w1 + 0.25f * w2;  // sm_z dy
                float gd = 0.25f * u0 + 0.5f * u1 + 0.25f * u2;  // sm_z dx
                sq[p - 2][gy_][gx_] = make_float4(gh, gw, gd, v11p);
            }
            v11p = a11;
        }
    }
    __syncthreads();

    // ---- Stage C: bilateral, 2 ADJACENT voxels/thread (2*tzh, 2*tzh+1) ----
    const int tx = t & 31;
    const int ty = (t >> 5) & 3;
    const int tzh = t >> 7;  // 0..1

    const float RC = LOG2E / (2.0f * 1.2f * 1.2f);  // range, log2e folded

    const int ox = X0 + tx;
    const int oy = Y0 + ty;
    const int oz0 = Z0 + tzh * 2;      // first voxel z
    const int oz1 = oz0 + 1;           // second (adjacent)

    // center packed grads: grad-local = tile-local + 1
    const float4 c0 = sq[tzh * 2 + 1][ty + 1][tx + 1];
    const float4 c1 = sq[tzh * 2 + 2][ty + 1][tx + 1];

    // clamped grad-local coords; 4 shared z-planes cover both voxels
    int nx[3], ny[3], nz[4];
#pragma unroll
    for (int d = 0; d < 3; ++d) {
        nx[d] = min(max(ox + d - 1, 0), NV - 1) - (X0 - 1);
        ny[d] = min(max(oy + d - 1, 0), NV - 1) - (Y0 - 1);
    }
#pragma unroll
    for (int p = 0; p < 4; ++p)
        nz[p] = min(max(oz0 + p - 1, 0), NV - 1) - (Z0 - 1);

    float num0 = 0.0f, den0 = 0.0f, num1 = 0.0f, den1 = 0.0f;

#pragma unroll
    for (int p = 0; p < 4; ++p) {  // absolute plane oz0-1+p
#pragma unroll
        for (int iy = 0; iy < 3; ++iy) {
#pragma unroll
            for (int ix = 0; ix < 3; ++ix) {
                float4 q = sq[nz[p]][ny[iy]][nx[ix]];
                if (p <= 2) {  // voxel0: dz = p-1
                    const float SDC =
                        -(float)((p - 1) * (p - 1) + (iy - 1) * (iy - 1) +
                                 (ix - 1) * (ix - 1)) *
                        (LOG2E / (2.0f * 120.0f * 120.0f));
                    float a = c0.x - q.x, b = c0.y - q.y, e = c0.z - q.z;
                    float g = a * a + b * b + e * e;
                    float w = __builtin_amdgcn_exp2f(fmaf(-g, RC, SDC));
                    num0 += w * q.w;
                    den0 += w;
                }
                if (p >= 1) {  // voxel1: dz = p-2
                    const float SDC =
                        -(float)((p - 2) * (p - 2) + (iy - 1) * (iy - 1) +
                                 (ix - 1) * (ix - 1)) *
                        (LOG2E / (2.0f * 120.0f * 120.0f));
                    float a = c1.x - q.x, b = c1.y - q.y, e = c1.z - q.z;
                    float g = a * a + b * b + e * e;
                    float w = __builtin_amdgcn_exp2f(fmaf(-g, RC, SDC));
                    num1 += w * q.w;
                    den1 += w;
                }
            }
        }
    }

    out[oz0 * NV2 + oy * NV + ox] = num0 / fmaxf(den0, 1e-8f);
    out[oz1 * NV2 + oy * NV + ox] = num1 / fmaxf(den1, 1e-8f);
}

extern "C" void kernel_launch(void* const* d_in, const int* in_sizes, int n_in,
                              void* d_out, int out_size, void* d_ws, size_t ws_size,
                              hipStream_t stream) {
    const float* vol = (const float*)d_in[0];
    float* out = (float*)d_out;

    dim3 grid(NV / TX, NV / TY, NV / TZ);  // 3 x 24 x 24 = 1728 blocks
    fused_bilateral_kernel<<<grid, dim3(256), 0, stream>>>(vol, out);
}